// Round 5
// baseline (243.591 us; speedup 1.0000x reference)
//
#include <hip/hip_runtime.h>
#include <hip/hip_bf16.h>
#include <stdint.h>

#define BM 128
#define BN 128
#define BK 64

typedef __attribute__((ext_vector_type(8))) short bf16x8;
typedef __attribute__((ext_vector_type(4))) float floatx4;

// ---- helpers ------------------------------------------------------------

__device__ __forceinline__ unsigned short f2bf(float f) {
    unsigned int x;
    __builtin_memcpy(&x, &f, 4);
    unsigned int r = (x + 0x7fffu + ((x >> 16) & 1u)) >> 16;  // RNE
    return (unsigned short)r;
}

__device__ __forceinline__ float bf2f_hi(unsigned int u_hi_masked) {
    float f;
    __builtin_memcpy(&f, &u_hi_masked, 4);
    return f;
}

// async global->LDS, 16B per lane.  LDS dest must be wave-uniform base + lane*16.
// R1 LESSON: the per-lane GLOBAL source order must stay ASCENDING — an XOR
// permutation within the 128B row segment de-coalesced the DMA into 16B
// requests and cost +60% on every staging-bound core (qk 50->80us).
__device__ __forceinline__ void async_copy16(const void* g, void* l) {
    __builtin_amdgcn_global_load_lds(
        (const __attribute__((address_space(1))) void*)(uintptr_t)g,
        (__attribute__((address_space(3))) void*)(uint32_t)(uintptr_t)l,
        16, 0, 0);
}

// ---- prep: fp32->bf16 convert of x  +  W^T bf16 of Wq/Wk/Wv -------------

__global__ __launch_bounds__(256) void prep(const float* __restrict__ x,
                                            const float* __restrict__ Wq,
                                            const float* __restrict__ Wk,
                                            const float* __restrict__ Wv,
                                            unsigned short* __restrict__ xb,
                                            unsigned short* __restrict__ wT) {
    __shared__ float tile[32][33];
    int bid = blockIdx.x;
    int tid = threadIdx.x;
    if (bid < 8192) {  // cvt: 8192 blocks x 256 threads x float4
        int i = bid * 256 + tid;
        float4 v = ((const float4*)x)[i];
        ushort4 o;
        o.x = f2bf(v.x);
        o.y = f2bf(v.y);
        o.z = f2bf(v.z);
        o.w = f2bf(v.w);
        ((ushort4*)xb)[i] = o;
    } else {  // transpose W: 3 x 1024 blocks, 32x32 tiles
        int w = bid - 8192;
        int z = w >> 10;
        int r = w & 1023;
        int bx = (r & 31) * 32;  // input col (n)
        int by = (r >> 5) * 32;  // input row (k)
        const float* W = z == 0 ? Wq : (z == 1 ? Wk : Wv);
        int tx = tid & 31, ty = tid >> 5;  // 32x8
        for (int rr = 0; rr < 32; rr += 8)
            tile[ty + rr][tx] = W[(size_t)(by + ty + rr) * 1024 + bx + tx];
        __syncthreads();
        unsigned short* o = wT + (size_t)z * 1024 * 1024;
        for (int rr = 0; rr < 32; rr += 8)
            o[(size_t)(bx + ty + rr) * 1024 + by + tx] = f2bf(tile[tx][ty + rr]);
    }
}

// ---- padded LDS layout (128^2 cores) ------------------------------------
// Segment = 8 tile-rows = one 1KB wave-DMA.  Segment STRIDE 544 shorts
// (512 data + 32 pad = 1088B = 272 dwords == 16 banks mod 32).  Fragment
// ds_read_b128 spans 2 adjacent segments; 16-bank parity shift + 4-bank kq
// shift -> conflict-free b128.  (R4: qk conflicts 12.58M -> 4.19M, -5us.)

#define SEG_STRIDE 544            // shorts: 512 data + 32 pad
#define BUF_SH (16 * SEG_STRIDE)  // 8704 shorts = 17408 B per 128x64 tile

// ---- GEMM core (single-buffer, padded) — s ------------------------------
// m97 structure (stage -> sync -> compute -> sync), 4 blocks/CU.

__device__ __forceinline__ void gemm_core(const unsigned short* __restrict__ A,
                                          int lda,
                                          const unsigned short* __restrict__ B,
                                          int ldb, void* __restrict__ C,
                                          int ldc, bool out_bf16, int kend,
                                          float scale, int m0, int n0) {
    __shared__ __align__(16) unsigned short As[BUF_SH];
    __shared__ __align__(16) unsigned short Bs[BUF_SH];

    int tid = threadIdx.x;
    int lane = tid & 63;
    int wave = tid >> 6;
    int wm = (wave >> 1) * 64;
    int wn = (wave & 1) * 64;
    int fr = lane & 15;  // fragment row (m) / col (n)
    int kq = lane >> 4;  // k-quad

    floatx4 acc[4][4] = {};

    for (int k0 = 0; k0 < kend; k0 += BK) {
#pragma unroll
        for (int q = 0; q < 4; q++) {
            int s = 4 * q + wave;         // 1KB segment, wave-uniform
            int r = s * 8 + (lane >> 3);  // global row
            int ko = (lane & 7) * 8;      // ascending chunk order!
            int dst = s * SEG_STRIDE + lane * 8;
            async_copy16(A + (size_t)(m0 + r) * lda + k0 + ko, &As[dst]);
            async_copy16(B + (size_t)(n0 + r) * ldb + k0 + ko, &Bs[dst]);
        }
        __syncthreads();  // drains vmcnt before LDS reads

#pragma unroll
        for (int kh = 0; kh < 2; kh++) {
            int kc = kh * 4 + kq;
            bf16x8 af[4], bfg[4];
#pragma unroll
            for (int mi = 0; mi < 4; mi++) {
                int row = wm + mi * 16 + fr;
                af[mi] = *(const bf16x8*)&As[(row >> 3) * SEG_STRIDE +
                                             (row & 7) * 64 + kc * 8];
            }
#pragma unroll
            for (int ni = 0; ni < 4; ni++) {
                int row = wn + ni * 16 + fr;
                bfg[ni] = *(const bf16x8*)&Bs[(row >> 3) * SEG_STRIDE +
                                              (row & 7) * 64 + kc * 8];
            }
#pragma unroll
            for (int mi = 0; mi < 4; mi++)
#pragma unroll
                for (int ni = 0; ni < 4; ni++)
                    acc[mi][ni] = __builtin_amdgcn_mfma_f32_16x16x32_bf16(
                        af[mi], bfg[ni], acc[mi][ni], 0, 0, 0);
        }
        __syncthreads();  // protect LDS before next stage
    }

    // epilogue: C/D layout col=lane&15, row=(lane>>4)*4+reg  (m89/m91-verified)
    int col0 = n0 + wn + fr;
    int rbase = m0 + wm + kq * 4;
    if (out_bf16) {
        unsigned short* Cb = (unsigned short*)C;
#pragma unroll
        for (int mi = 0; mi < 4; mi++)
#pragma unroll
            for (int ni = 0; ni < 4; ni++)
#pragma unroll
                for (int r = 0; r < 4; r++)
                    Cb[(size_t)(rbase + mi * 16 + r) * ldc + col0 + ni * 16] =
                        f2bf(acc[mi][ni][r] * scale);
    } else {
        float* Cb = (float*)C;
#pragma unroll
        for (int mi = 0; mi < 4; mi++)
#pragma unroll
            for (int ni = 0; ni < 4; ni++)
#pragma unroll
                for (int r = 0; r < 4; r++)
                    Cb[(size_t)(rbase + mi * 16 + r) * ldc + col0 + ni * 16] =
                        acc[mi][ni][r] * scale;
    }
}

// ---- GEMM core (double-buffered, padded) — pv / vt ----------------------
// R3-verified.  2-phase dbuf: stage(t+1) before compute(t), ONE
// __syncthreads() per K-step.  LDS 4 x 17408B = 69632B; 2 blocks/CU.

__device__ __forceinline__ void gemm_core_db(
    const unsigned short* __restrict__ A, int lda,
    const unsigned short* __restrict__ B, int ldb, void* __restrict__ C,
    int ldc, bool out_bf16, int kend, float scale, int m0, int n0) {
    __shared__ __align__(16) unsigned short As[2 * BUF_SH];
    __shared__ __align__(16) unsigned short Bs[2 * BUF_SH];

    int tid = threadIdx.x;
    int lane = tid & 63;
    int wave = tid >> 6;
    int wm = (wave >> 1) * 64;
    int wn = (wave & 1) * 64;
    int fr = lane & 15;  // fragment row (m) / col (n)
    int kq = lane >> 4;  // k-quad

    floatx4 acc[4][4] = {};

    auto stage = [&](int buf, int k0) {
#pragma unroll
        for (int q = 0; q < 4; q++) {
            int s = 4 * q + wave;         // 1KB segment, wave-uniform
            int r = s * 8 + (lane >> 3);  // global row
            int ko = (lane & 7) * 8;      // ascending chunk order!
            int dst = buf * BUF_SH + s * SEG_STRIDE + lane * 8;
            async_copy16(A + (size_t)(m0 + r) * lda + k0 + ko, &As[dst]);
            async_copy16(B + (size_t)(n0 + r) * ldb + k0 + ko, &Bs[dst]);
        }
    };

    auto compute = [&](int buf) {
        const unsigned short* as = &As[buf * BUF_SH];
        const unsigned short* bs = &Bs[buf * BUF_SH];
#pragma unroll
        for (int kh = 0; kh < 2; kh++) {
            int kc = kh * 4 + kq;
            bf16x8 af[4], bfg[4];
#pragma unroll
            for (int mi = 0; mi < 4; mi++) {
                int row = wm + mi * 16 + fr;
                af[mi] = *(const bf16x8*)&as[(row >> 3) * SEG_STRIDE +
                                             (row & 7) * 64 + kc * 8];
            }
#pragma unroll
            for (int ni = 0; ni < 4; ni++) {
                int row = wn + ni * 16 + fr;
                bfg[ni] = *(const bf16x8*)&bs[(row >> 3) * SEG_STRIDE +
                                              (row & 7) * 64 + kc * 8];
            }
#pragma unroll
            for (int mi = 0; mi < 4; mi++)
#pragma unroll
                for (int ni = 0; ni < 4; ni++)
                    acc[mi][ni] = __builtin_amdgcn_mfma_f32_16x16x32_bf16(
                        af[mi], bfg[ni], acc[mi][ni], 0, 0, 0);
        }
    };

    stage(0, 0);
    __syncthreads();
    int nt = kend / BK;
    int cur = 0;
    for (int t = 0; t < nt; t++) {
        if (t + 1 < nt) stage(cur ^ 1, (t + 1) * BK);
        compute(cur);
        __syncthreads();
        cur ^= 1;
    }

    int col0 = n0 + wn + fr;
    int rbase = m0 + wm + kq * 4;
    if (out_bf16) {
        unsigned short* Cb = (unsigned short*)C;
#pragma unroll
        for (int mi = 0; mi < 4; mi++)
#pragma unroll
            for (int ni = 0; ni < 4; ni++)
#pragma unroll
                for (int r = 0; r < 4; r++)
                    Cb[(size_t)(rbase + mi * 16 + r) * ldc + col0 + ni * 16] =
                        f2bf(acc[mi][ni][r] * scale);
    } else {
        float* Cb = (float*)C;
#pragma unroll
        for (int mi = 0; mi < 4; mi++)
#pragma unroll
            for (int ni = 0; ni < 4; ni++)
#pragma unroll
                for (int r = 0; r < 4; r++)
                    Cb[(size_t)(rbase + mi * 16 + r) * ldc + col0 + ni * 16] =
                        acc[mi][ni][r] * scale;
    }
}

// ---- stage B (R5): qk = xb @ [Wq|Wk] — 256^2 tile, counted-vmcnt pipeline
// M=8192 N=2048 K=1024 -> grid (8,32) = 256 blocks = EXACTLY 1/CU.
// 512 threads, 8 waves (2M x 4N): wave output 128x64 = acc[8][4].
// BK=32, 4 K-tile LDS buffers (4 x 32KB = 128KB), linear [256][32] layout:
//   row = 64B = 16 banks -> fragment b128 lanes (fr,kq) hit bank
//   16(fr&1)+4kq: all 8 groups x 8 lanes = CONFLICT-FREE, zero padding,
//   linear 1KB wave-DMAs (16 rows x 64B, ascending — R1-safe).
// Pipeline: while computing K-tile j, stage A(j+3) (phase 0) and B(j+3)
// (phase 1) into buf[(j+3)&3] = buf freed by j-1 (its reads drained by the
// compiler's lgkmcnt before j-1's last MFMA, which precedes the barrier we
// issue stages behind).  Publish: vmcnt(8) at phase 1 (retires through
// K-tile j+1 = all loads read next; leaves j+2/j+3's 8 DMA instrs in
// flight — NEVER drains to 0 in steady state, the T4 lever).  Tail:
// vmcnt(8/4/0) at j=28/29/30.  Raw s_barrier only (no __syncthreads =
// no hidden vmcnt(0) drains); sched_barrier(0) after each barrier pins
// hoisting (rule #18); setprio(1) around MFMA clusters (T5).
// Per K-tile: 2 phases x {8 ds_read_b128, 1 stage (2 DMA), barrier,
// 16 MFMA, barrier}.  MFMA floor 13.8us; LDS floor ~17us; target 25-30us.

__global__ __launch_bounds__(512, 2) void gemm_qk8(
    const unsigned short* __restrict__ A, const unsigned short* __restrict__ B,
    unsigned short* __restrict__ C) {
    __shared__ __align__(16) unsigned short lds[4][16384];  // 128 KB

    const int tid = threadIdx.x;
    const int lane = tid & 63;
    const int wave = tid >> 6;
    const int wr = wave >> 2;  // 0..1  (m half)
    const int wc = wave & 3;   // 0..3  (n quarter)
    const int fr = lane & 15;
    const int kq = lane >> 4;
    const int m0 = blockIdx.y * 256;
    const int n0 = blockIdx.x * 256;

    // staging: per wave 2 segments/operand; seg = 16 rows x 32 cols = 1KB.
    // lane -> (row = seg*16 + lane/4, col = (lane&3)*8), ascending source.
    const unsigned short* aS0 =
        A + (size_t)(m0 + wave * 32 + (lane >> 2)) * 1024 + (lane & 3) * 8;
    const unsigned short* aS1 = aS0 + 16 * 1024;
    const unsigned short* bS0 =
        B + (size_t)(n0 + wave * 32 + (lane >> 2)) * 1024 + (lane & 3) * 8;
    const unsigned short* bS1 = bS0 + 16 * 1024;
    const int dA0 = wave * 2 * 512 + lane * 8;  // A area: [0, 8192)
    const int dA1 = dA0 + 512;
    const int dB0 = 8192 + dA0;  // B area: [8192, 16384)
    const int dB1 = 8192 + dA1;

    floatx4 acc[8][4] = {};

    auto stageA = [&](int j) {
        unsigned short* d = &lds[j & 3][0];
        int kk = j * 32;
        async_copy16(aS0 + kk, d + dA0);
        async_copy16(aS1 + kk, d + dA1);
    };
    auto stageB = [&](int j) {
        unsigned short* d = &lds[j & 3][0];
        int kk = j * 32;
        async_copy16(bS0 + kk, d + dB0);
        async_copy16(bS1 + kk, d + dB1);
    };

    // prologue: K-tiles 0..2 (12 DMA instrs); retire tile 0 (leave 8)
    stageA(0); stageB(0);
    stageA(1); stageB(1);
    stageA(2); stageB(2);
    asm volatile("s_waitcnt vmcnt(8)" ::: "memory");
    __builtin_amdgcn_s_barrier();
    __builtin_amdgcn_sched_barrier(0);

    for (int j = 0; j < 32; ++j) {
        const unsigned short* as = &lds[j & 3][0];
        const unsigned short* bs = as + 8192;
        bf16x8 af[4], bfr[4];

        // ---- phase 0: rows wr*128 + [0,64) ----
#pragma unroll
        for (int mi = 0; mi < 4; mi++)
            af[mi] = *(const bf16x8*)&as[(wr * 128 + mi * 16 + fr) * 32 + kq * 8];
#pragma unroll
        for (int ni = 0; ni < 4; ni++)
            bfr[ni] = *(const bf16x8*)&bs[(wc * 64 + ni * 16 + fr) * 32 + kq * 8];
        if (j + 3 < 32) stageA(j + 3);
        __builtin_amdgcn_s_barrier();
        __builtin_amdgcn_sched_barrier(0);
        __builtin_amdgcn_s_setprio(1);
#pragma unroll
        for (int mi = 0; mi < 4; mi++)
#pragma unroll
            for (int ni = 0; ni < 4; ni++)
                acc[mi][ni] = __builtin_amdgcn_mfma_f32_16x16x32_bf16(
                    af[mi], bfr[ni], acc[mi][ni], 0, 0, 0);
        __builtin_amdgcn_s_setprio(0);
        __builtin_amdgcn_s_barrier();
        __builtin_amdgcn_sched_barrier(0);

        // ---- phase 1: rows wr*128 + [64,128) ----
#pragma unroll
        for (int mi = 0; mi < 4; mi++)
            af[mi] = *(const bf16x8*)&as[(wr * 128 + 64 + mi * 16 + fr) * 32 +
                                         kq * 8];
#pragma unroll
        for (int ni = 0; ni < 4; ni++)
            bfr[ni] = *(const bf16x8*)&bs[(wc * 64 + ni * 16 + fr) * 32 + kq * 8];
        if (j + 3 < 32) stageB(j + 3);
        // publish K-tile j+1 for next iteration's reads (counted, not 0)
        if (j <= 28) {
            asm volatile("s_waitcnt vmcnt(8)" ::: "memory");
        } else if (j == 29) {
            asm volatile("s_waitcnt vmcnt(4)" ::: "memory");
        } else if (j == 30) {
            asm volatile("s_waitcnt vmcnt(0)" ::: "memory");
        }
        __builtin_amdgcn_s_barrier();
        __builtin_amdgcn_sched_barrier(0);
        __builtin_amdgcn_s_setprio(1);
#pragma unroll
        for (int mi = 0; mi < 4; mi++)
#pragma unroll
            for (int ni = 0; ni < 4; ni++)
                acc[4 + mi][ni] = __builtin_amdgcn_mfma_f32_16x16x32_bf16(
                    af[mi], bfr[ni], acc[4 + mi][ni], 0, 0, 0);
        __builtin_amdgcn_s_setprio(0);
        __builtin_amdgcn_s_barrier();
        __builtin_amdgcn_sched_barrier(0);
    }

    // epilogue: C/D layout col=lane&15, row=(lane>>4)*4+reg
    const int col0 = n0 + wc * 64 + fr;
    const int rbase = m0 + wr * 128 + kq * 4;
#pragma unroll
    for (int a = 0; a < 8; a++)
#pragma unroll
        for (int ni = 0; ni < 4; ni++)
#pragma unroll
            for (int r = 0; r < 4; r++)
                C[(size_t)(rbase + a * 16 + r) * 2048 + col0 + ni * 16] =
                    f2bf(acc[a][ni][r]);
}

// ---- triangular job decode for the S stage ------------------------------

__device__ __forceinline__ void tri_decode(int r2, int& mb, int& nb) {
    mb = (int)((sqrtf(8.0f * r2 + 1.0f) - 1.0f) * 0.5f);
    while ((mb + 1) * (mb + 2) / 2 <= r2) mb++;
    while (mb * (mb + 1) / 2 > r2) mb--;
    nb = r2 - mb * (mb + 1) / 2;
}

// ---- stage C: S = scale * Q K^T, lower-triangle blocks only -------------
// 544 blocks; max CU gets 3 blocks = 48 iters.

__global__ __launch_bounds__(256, 4) void gemm_s(
    const unsigned short* __restrict__ qk, unsigned short* __restrict__ S) {
    int bz = blockIdx.x / 136;
    int mb, nb;
    tri_decode(blockIdx.x - bz * 136, mb, nb);
    const unsigned short* Q = qk + (size_t)bz * 2048 * 2048;
    gemm_core(Q, 2048, Q + 1024, 2048, S + (size_t)bz * 2048 * 2048, 2048,
              true, 1024, 0.03125f, mb * BM, nb * BN);
}

// ---- stage D: softmax (causal, in place)  MERGED WITH  vt = WvT @ xb^T --
// Softmax: ONE row per wave (2048 blocks x 4 waves = 8192 rows exactly).

__global__ __launch_bounds__(256, 4) void sm_vt(
    unsigned short* __restrict__ S, const unsigned short* __restrict__ wTv,
    const unsigned short* __restrict__ xb, unsigned short* __restrict__ vt) {
    int bid = blockIdx.x;
    if (bid < 512) {  // vt: 8 m-blocks x 64 n-blocks (M=1024 WvT, N=8192 xb)
        gemm_core_db(wTv, 1024, xb, 1024, vt, 8192, true, 1024, 1.0f,
                     (bid >> 6) * BM, (bid & 63) * BN);
        return;
    }
    // softmax: one wave per row, full row in registers (32 f32/lane)
    int lane = threadIdx.x & 63;
    int row = (bid - 512) * 4 + (threadIdx.x >> 6);  // 0..8191
    int i = row & 2047;  // causal row index within batch
    unsigned short* s = S + (size_t)row * 2048;

    uint4 raw[4];
#pragma unroll
    for (int c = 0; c < 4; c++) raw[c] = ((const uint4*)s)[lane + c * 64];

    const float NEG = -1.0e30f;
    float p[32];
    float m = NEG;
#pragma unroll
    for (int c = 0; c < 4; c++) {
        const unsigned int* u = (const unsigned int*)&raw[c];
#pragma unroll
        for (int w = 0; w < 4; w++) {
            int j = c * 512 + lane * 8 + w * 2;
            float f0 = bf2f_hi(u[w] << 16);
            float f1 = bf2f_hi(u[w] & 0xffff0000u);
            f0 = (j <= i) ? f0 : NEG;
            f1 = (j + 1 <= i) ? f1 : NEG;
            p[c * 8 + w * 2] = f0;
            p[c * 8 + w * 2 + 1] = f1;
            m = fmaxf(m, fmaxf(f0, f1));
        }
    }
#pragma unroll
    for (int o = 32; o > 0; o >>= 1) m = fmaxf(m, __shfl_xor(m, o));

    float sum = 0.f;
#pragma unroll
    for (int t = 0; t < 32; t++) {
        p[t] = __expf(p[t] - m);
        sum += p[t];
    }
#pragma unroll
    for (int o = 32; o > 0; o >>= 1) sum += __shfl_xor(sum, o);
    float inv = 1.0f / sum;

#pragma unroll
    for (int c = 0; c < 4; c++) {
        uint4 out;
        unsigned int* u = (unsigned int*)&out;
#pragma unroll
        for (int w = 0; w < 4; w++) {
            unsigned int lo = f2bf(p[c * 8 + w * 2] * inv);
            unsigned int hi = f2bf(p[c * 8 + w * 2 + 1] * inv);
            u[w] = lo | (hi << 16);
        }
        ((uint4*)s)[lane + c * 64] = out;
    }
}

// ---- stage E: O = P @ V, complementary kend pairing ---------------------
// Round-robin block->CU: CU c gets blocks c and c+256; per-CU iters = 34,
// uniform.  R3 dbuf core + padded-stride layout.

__global__ __launch_bounds__(256, 4) void gemm_pv(
    const unsigned short* __restrict__ S, const unsigned short* __restrict__ vt,
    float* __restrict__ out) {
    int b = blockIdx.x;
    int j = b < 256 ? b : 767 - b;
    int mb = j >> 5;
    int rem = j & 31;
    int bz = rem >> 3, nb = rem & 7;
    int kend = (mb + 1) * 128;  // P[i][j]==0 for j>i
    gemm_core_db(S + (size_t)bz * 2048 * 2048, 2048, vt + (size_t)bz * 2048,
                 8192, out + (size_t)bz * 2048 * 1024, 1024, false, kend, 1.0f,
                 mb * BM, nb * BN);
}

// ---- launch -------------------------------------------------------------

extern "C" void kernel_launch(void* const* d_in, const int* in_sizes, int n_in,
                              void* d_out, int out_size, void* d_ws,
                              size_t ws_size, hipStream_t stream) {
    const float* x = (const float*)d_in[0];
    const float* Wq = (const float*)d_in[1];
    const float* Wk = (const float*)d_in[2];
    const float* Wv = (const float*)d_in[3];
    // causal_mask (d_in[4]) is always 1 in this problem — hardcoded causal.

    char* ws = (char*)d_ws;
    // layout (bytes):
    //   qk [8192][2048] bf16  : 0        .. 33554432   (Q cols 0..1023, K cols 1024..2047)
    //   S  [4][2048][2048]    : 33554432 .. 67108864
    //   vt [1024][8192] bf16  : 67108864 .. 83886080   (V^T, batches side-by-side cols)
    //   xb [8192][1024] bf16  : 83886080 .. 100663296
    //   wT [3][1024][1024]    : 100663296.. 106954752
    unsigned short* qk = (unsigned short*)(ws);
    unsigned short* S = (unsigned short*)(ws + 33554432);
    unsigned short* vt = (unsigned short*)(ws + 67108864);
    unsigned short* xb = (unsigned short*)(ws + 83886080);
    unsigned short* wT = (unsigned short*)(ws + 100663296);

    // A. x->bf16 (8192 blocks) + W->W^T bf16 (3072 blocks), one dispatch
    prep<<<11264, 256, 0, stream>>>(x, Wq, Wk, Wv, xb, wT);
    // B. qk = xb @ [Wq|Wk]   (M=8192, N=2048, K=1024) — 256 blocks, 1/CU
    gemm_qk8<<<dim3(8, 32), 512, 0, stream>>>(xb, wT, qk);
    // C. S = scale * Q K^T — 544 lower-triangle blocks only
    gemm_s<<<544, 256, 0, stream>>>(qk, S);
    // D. softmax (2048 light blocks) + vt GEMM (512 blocks), one dispatch
    sm_vt<<<2560, 256, 0, stream>>>(S, wT + 2 * 1024 * 1024, xb, vt);
    // E. O = P @ V — 512 blocks, complementary kend pairing
    gemm_pv<<<512, 256, 0, stream>>>(S, vt, (float*)d_out);
}

// Round 6
// 235.334 us; speedup vs baseline: 1.0351x; 1.0351x over previous
//
#include <hip/hip_runtime.h>
#include <hip/hip_bf16.h>
#include <stdint.h>

#define BM 128
#define BN 128
#define BK 64

typedef __attribute__((ext_vector_type(8))) short bf16x8;
typedef __attribute__((ext_vector_type(4))) float floatx4;

// ---- helpers ------------------------------------------------------------

__device__ __forceinline__ unsigned short f2bf(float f) {
    unsigned int x;
    __builtin_memcpy(&x, &f, 4);
    unsigned int r = (x + 0x7fffu + ((x >> 16) & 1u)) >> 16;  // RNE
    return (unsigned short)r;
}

__device__ __forceinline__ float bf2f_hi(unsigned int u_hi_masked) {
    float f;
    __builtin_memcpy(&f, &u_hi_masked, 4);
    return f;
}

// async global->LDS, 16B per lane.  LDS dest must be wave-uniform base + lane*16.
// R1 LESSON: the per-lane GLOBAL source order must stay ASCENDING — an XOR
// permutation within the 128B row segment de-coalesced the DMA into 16B
// requests and cost +60% on every staging-bound core (qk 50->80us).
__device__ __forceinline__ void async_copy16(const void* g, void* l) {
    __builtin_amdgcn_global_load_lds(
        (const __attribute__((address_space(1))) void*)(uintptr_t)g,
        (__attribute__((address_space(3))) void*)(uint32_t)(uintptr_t)l,
        16, 0, 0);
}

// ---- prep: fp32->bf16 convert of x  +  W^T bf16 of Wq/Wk/Wv -------------

__global__ __launch_bounds__(256) void prep(const float* __restrict__ x,
                                            const float* __restrict__ Wq,
                                            const float* __restrict__ Wk,
                                            const float* __restrict__ Wv,
                                            unsigned short* __restrict__ xb,
                                            unsigned short* __restrict__ wT) {
    __shared__ float tile[32][33];
    int bid = blockIdx.x;
    int tid = threadIdx.x;
    if (bid < 8192) {  // cvt: 8192 blocks x 256 threads x float4
        int i = bid * 256 + tid;
        float4 v = ((const float4*)x)[i];
        ushort4 o;
        o.x = f2bf(v.x);
        o.y = f2bf(v.y);
        o.z = f2bf(v.z);
        o.w = f2bf(v.w);
        ((ushort4*)xb)[i] = o;
    } else {  // transpose W: 3 x 1024 blocks, 32x32 tiles
        int w = bid - 8192;
        int z = w >> 10;
        int r = w & 1023;
        int bx = (r & 31) * 32;  // input col (n)
        int by = (r >> 5) * 32;  // input row (k)
        const float* W = z == 0 ? Wq : (z == 1 ? Wk : Wv);
        int tx = tid & 31, ty = tid >> 5;  // 32x8
        for (int rr = 0; rr < 32; rr += 8)
            tile[ty + rr][tx] = W[(size_t)(by + ty + rr) * 1024 + bx + tx];
        __syncthreads();
        unsigned short* o = wT + (size_t)z * 1024 * 1024;
        for (int rr = 0; rr < 32; rr += 8)
            o[(size_t)(bx + ty + rr) * 1024 + by + tx] = f2bf(tile[tx][ty + rr]);
    }
}

// ---- padded LDS layout (128^2 cores) ------------------------------------
// Segment = 8 tile-rows = one 1KB wave-DMA.  Segment STRIDE 544 shorts
// (512 data + 32 pad = 1088B = 272 dwords == 16 banks mod 32).  Fragment
// ds_read_b128 spans 2 adjacent segments; 16-bank parity shift + 4-bank kq
// shift -> conflict-free b128.  NOTE (R5): the residual 4.19M conflict
// count (= 4 cyc per b128 read, layout-invariant) is the intrinsic b128
// overhead m134 measured (12 cyc vs 8 ideal) — NOT fixable by layout.

#define SEG_STRIDE 544            // shorts: 512 data + 32 pad
#define BUF_SH (16 * SEG_STRIDE)  // 8704 shorts = 17408 B per 128x64 tile

// ---- GEMM core (single-buffer, padded) — s ------------------------------
// m97 structure (stage -> sync -> compute -> sync), 4 blocks/CU.

__device__ __forceinline__ void gemm_core(const unsigned short* __restrict__ A,
                                          int lda,
                                          const unsigned short* __restrict__ B,
                                          int ldb, void* __restrict__ C,
                                          int ldc, bool out_bf16, int kend,
                                          float scale, int m0, int n0) {
    __shared__ __align__(16) unsigned short As[BUF_SH];
    __shared__ __align__(16) unsigned short Bs[BUF_SH];

    int tid = threadIdx.x;
    int lane = tid & 63;
    int wave = tid >> 6;
    int wm = (wave >> 1) * 64;
    int wn = (wave & 1) * 64;
    int fr = lane & 15;  // fragment row (m) / col (n)
    int kq = lane >> 4;  // k-quad

    floatx4 acc[4][4] = {};

    for (int k0 = 0; k0 < kend; k0 += BK) {
#pragma unroll
        for (int q = 0; q < 4; q++) {
            int s = 4 * q + wave;         // 1KB segment, wave-uniform
            int r = s * 8 + (lane >> 3);  // global row
            int ko = (lane & 7) * 8;      // ascending chunk order!
            int dst = s * SEG_STRIDE + lane * 8;
            async_copy16(A + (size_t)(m0 + r) * lda + k0 + ko, &As[dst]);
            async_copy16(B + (size_t)(n0 + r) * ldb + k0 + ko, &Bs[dst]);
        }
        __syncthreads();  // drains vmcnt before LDS reads

#pragma unroll
        for (int kh = 0; kh < 2; kh++) {
            int kc = kh * 4 + kq;
            bf16x8 af[4], bfg[4];
#pragma unroll
            for (int mi = 0; mi < 4; mi++) {
                int row = wm + mi * 16 + fr;
                af[mi] = *(const bf16x8*)&As[(row >> 3) * SEG_STRIDE +
                                             (row & 7) * 64 + kc * 8];
            }
#pragma unroll
            for (int ni = 0; ni < 4; ni++) {
                int row = wn + ni * 16 + fr;
                bfg[ni] = *(const bf16x8*)&Bs[(row >> 3) * SEG_STRIDE +
                                              (row & 7) * 64 + kc * 8];
            }
#pragma unroll
            for (int mi = 0; mi < 4; mi++)
#pragma unroll
                for (int ni = 0; ni < 4; ni++)
                    acc[mi][ni] = __builtin_amdgcn_mfma_f32_16x16x32_bf16(
                        af[mi], bfg[ni], acc[mi][ni], 0, 0, 0);
        }
        __syncthreads();  // protect LDS before next stage
    }

    // epilogue: C/D layout col=lane&15, row=(lane>>4)*4+reg  (m89/m91-verified)
    int col0 = n0 + wn + fr;
    int rbase = m0 + wm + kq * 4;
    if (out_bf16) {
        unsigned short* Cb = (unsigned short*)C;
#pragma unroll
        for (int mi = 0; mi < 4; mi++)
#pragma unroll
            for (int ni = 0; ni < 4; ni++)
#pragma unroll
                for (int r = 0; r < 4; r++)
                    Cb[(size_t)(rbase + mi * 16 + r) * ldc + col0 + ni * 16] =
                        f2bf(acc[mi][ni][r] * scale);
    } else {
        float* Cb = (float*)C;
#pragma unroll
        for (int mi = 0; mi < 4; mi++)
#pragma unroll
            for (int ni = 0; ni < 4; ni++)
#pragma unroll
                for (int r = 0; r < 4; r++)
                    Cb[(size_t)(rbase + mi * 16 + r) * ldc + col0 + ni * 16] =
                        acc[mi][ni][r] * scale;
    }
}

// ---- GEMM core (double-buffered, padded) — pv / vt ----------------------
// R3-verified.  2-phase dbuf: stage(t+1) before compute(t), ONE
// __syncthreads() per K-step.  LDS 4 x 17408B = 69632B; 2 blocks/CU.

__device__ __forceinline__ void gemm_core_db(
    const unsigned short* __restrict__ A, int lda,
    const unsigned short* __restrict__ B, int ldb, void* __restrict__ C,
    int ldc, bool out_bf16, int kend, float scale, int m0, int n0) {
    __shared__ __align__(16) unsigned short As[2 * BUF_SH];
    __shared__ __align__(16) unsigned short Bs[2 * BUF_SH];

    int tid = threadIdx.x;
    int lane = tid & 63;
    int wave = tid >> 6;
    int wm = (wave >> 1) * 64;
    int wn = (wave & 1) * 64;
    int fr = lane & 15;  // fragment row (m) / col (n)
    int kq = lane >> 4;  // k-quad

    floatx4 acc[4][4] = {};

    auto stage = [&](int buf, int k0) {
#pragma unroll
        for (int q = 0; q < 4; q++) {
            int s = 4 * q + wave;         // 1KB segment, wave-uniform
            int r = s * 8 + (lane >> 3);  // global row
            int ko = (lane & 7) * 8;      // ascending chunk order!
            int dst = buf * BUF_SH + s * SEG_STRIDE + lane * 8;
            async_copy16(A + (size_t)(m0 + r) * lda + k0 + ko, &As[dst]);
            async_copy16(B + (size_t)(n0 + r) * ldb + k0 + ko, &Bs[dst]);
        }
    };

    auto compute = [&](int buf) {
        const unsigned short* as = &As[buf * BUF_SH];
        const unsigned short* bs = &Bs[buf * BUF_SH];
#pragma unroll
        for (int kh = 0; kh < 2; kh++) {
            int kc = kh * 4 + kq;
            bf16x8 af[4], bfg[4];
#pragma unroll
            for (int mi = 0; mi < 4; mi++) {
                int row = wm + mi * 16 + fr;
                af[mi] = *(const bf16x8*)&as[(row >> 3) * SEG_STRIDE +
                                             (row & 7) * 64 + kc * 8];
            }
#pragma unroll
            for (int ni = 0; ni < 4; ni++) {
                int row = wn + ni * 16 + fr;
                bfg[ni] = *(const bf16x8*)&bs[(row >> 3) * SEG_STRIDE +
                                              (row & 7) * 64 + kc * 8];
            }
#pragma unroll
            for (int mi = 0; mi < 4; mi++)
#pragma unroll
                for (int ni = 0; ni < 4; ni++)
                    acc[mi][ni] = __builtin_amdgcn_mfma_f32_16x16x32_bf16(
                        af[mi], bfg[ni], acc[mi][ni], 0, 0, 0);
        }
    };

    stage(0, 0);
    __syncthreads();
    int nt = kend / BK;
    int cur = 0;
    for (int t = 0; t < nt; t++) {
        if (t + 1 < nt) stage(cur ^ 1, (t + 1) * BK);
        compute(cur);
        __syncthreads();
        cur ^= 1;
    }

    int col0 = n0 + wn + fr;
    int rbase = m0 + wm + kq * 4;
    if (out_bf16) {
        unsigned short* Cb = (unsigned short*)C;
#pragma unroll
        for (int mi = 0; mi < 4; mi++)
#pragma unroll
            for (int ni = 0; ni < 4; ni++)
#pragma unroll
                for (int r = 0; r < 4; r++)
                    Cb[(size_t)(rbase + mi * 16 + r) * ldc + col0 + ni * 16] =
                        f2bf(acc[mi][ni][r] * scale);
    } else {
        float* Cb = (float*)C;
#pragma unroll
        for (int mi = 0; mi < 4; mi++)
#pragma unroll
            for (int ni = 0; ni < 4; ni++)
#pragma unroll
                for (int r = 0; r < 4; r++)
                    Cb[(size_t)(rbase + mi * 16 + r) * ldc + col0 + ni * 16] =
                        acc[mi][ni][r] * scale;
    }
}

// ---- stage B (R6): qk = xb @ [Wq|Wk] — 256^2, ONE barrier per K-tile ----
// R5 failed (50us vs R4's 42) from schedule overhead: 4 barriers + 6
// sched_barrier(0) per K-tile = the m141 anti-pattern.  R6 exploits what
// the 4-deep buffer rotation actually buys: buffer (j+3)&3 == (j-1)&3 was
// last READ in iter j-1, so ONE {vmcnt(N); s_barrier} at the top of iter j
// guarantees (a) tile j landed for all waves (each wave's own vmcnt +
// barrier), (b) all waves finished reading j-1 (program order).  No other
// barriers; no sched_barrier; compiler free to interleave ds_read / DMA
// issue / MFMA (its lgkm insertion is near-optimal per the m97 asm study).
// Barriers are inline-asm with "memory" clobber (raw builtin s_barrier has
// no compiler fence -> reads could hoist above the sync).
// vmcnt (top of iter j, counts own-wave 4-DMAs/tile): steady in-flight =
// {t(j),t(j+1),t(j+2)} = 12 -> vmcnt(8) retires tile j.  Staging stops
// after j=28 (stages t31): j=30 in-flight {t30,t31}=8 -> vmcnt(4);
// j=31 in-flight {t31}=4 -> vmcnt(0).  Never drains mid-loop (T4).
// Geometry (R5-verified correct + FETCH == R4 -> DMA coalescing OK):
// grid (8,32)=256 blocks=1/CU, 512 thr, 8 waves (2M x 4N), wave tile
// 128x64, BK=32, 4 x 32KB linear [256][32] LDS (row=64B=16 banks ->
// fragment lanes cover all 8 4-bank groups, conflict-free-by-construction).

__global__ __launch_bounds__(512, 2) void gemm_qk8(
    const unsigned short* __restrict__ A, const unsigned short* __restrict__ B,
    unsigned short* __restrict__ C) {
    __shared__ __align__(16) unsigned short lds[4][16384];  // 128 KB

    const int tid = threadIdx.x;
    const int lane = tid & 63;
    const int wave = tid >> 6;
    const int wr = wave >> 2;  // 0..1  (m half)
    const int wc = wave & 3;   // 0..3  (n quarter)
    const int fr = lane & 15;
    const int kq = lane >> 4;
    const int m0 = blockIdx.y * 256;
    const int n0 = blockIdx.x * 256;

    // staging: per wave 2 segments/operand; seg = 16 rows x 32 cols = 1KB.
    // lane -> (row = seg*16 + lane/4, col = (lane&3)*8): ascending source.
    const unsigned short* aS0 =
        A + (size_t)(m0 + wave * 32 + (lane >> 2)) * 1024 + (lane & 3) * 8;
    const unsigned short* aS1 = aS0 + 16 * 1024;
    const unsigned short* bS0 =
        B + (size_t)(n0 + wave * 32 + (lane >> 2)) * 1024 + (lane & 3) * 8;
    const unsigned short* bS1 = bS0 + 16 * 1024;
    const int dA0 = wave * 1024 + lane * 8;  // A area: [0, 8192) shorts
    const int dA1 = dA0 + 512;
    const int dB0 = 8192 + dA0;  // B area: [8192, 16384)
    const int dB1 = 8192 + dA1;

    floatx4 acc[8][4] = {};

    auto stageA = [&](int j) {
        unsigned short* d = &lds[j & 3][0];
        int kk = j * 32;
        async_copy16(aS0 + kk, d + dA0);
        async_copy16(aS1 + kk, d + dA1);
    };
    auto stageB = [&](int j) {
        unsigned short* d = &lds[j & 3][0];
        int kk = j * 32;
        async_copy16(bS0 + kk, d + dB0);
        async_copy16(bS1 + kk, d + dB1);
    };

    // prologue: K-tiles 0..2 in flight (12 DMA instrs/wave)
    stageA(0); stageB(0);
    stageA(1); stageB(1);
    stageA(2); stageB(2);

    for (int j = 0; j < 32; ++j) {
        // ---- the ONLY sync point of the K-tile ----
        if (j < 30) {
            asm volatile("s_waitcnt vmcnt(8)" ::: "memory");
        } else if (j == 30) {
            asm volatile("s_waitcnt vmcnt(4)" ::: "memory");
        } else {
            asm volatile("s_waitcnt vmcnt(0)" ::: "memory");
        }
        asm volatile("s_barrier" ::: "memory");

        const unsigned short* as = &lds[j & 3][0];
        const unsigned short* bs = as + 8192;
        bf16x8 af[4], bfr[4];

        // ---- phase 0: rows wr*128 + [0,64) ----
#pragma unroll
        for (int mi = 0; mi < 4; mi++)
            af[mi] = *(const bf16x8*)&as[(wr * 128 + mi * 16 + fr) * 32 + kq * 8];
#pragma unroll
        for (int ni = 0; ni < 4; ni++)
            bfr[ni] = *(const bf16x8*)&bs[(wc * 64 + ni * 16 + fr) * 32 + kq * 8];
        if (j + 3 < 32) stageA(j + 3);  // writes buf (j-1)&3: readers done
        __builtin_amdgcn_s_setprio(1);
#pragma unroll
        for (int mi = 0; mi < 4; mi++)
#pragma unroll
            for (int ni = 0; ni < 4; ni++)
                acc[mi][ni] = __builtin_amdgcn_mfma_f32_16x16x32_bf16(
                    af[mi], bfr[ni], acc[mi][ni], 0, 0, 0);
        __builtin_amdgcn_s_setprio(0);

        // ---- phase 1: rows wr*128 + [64,128) ----
#pragma unroll
        for (int mi = 0; mi < 4; mi++)
            af[mi] = *(const bf16x8*)&as[(wr * 128 + 64 + mi * 16 + fr) * 32 +
                                         kq * 8];
#pragma unroll
        for (int ni = 0; ni < 4; ni++)
            bfr[ni] = *(const bf16x8*)&bs[(wc * 64 + ni * 16 + fr) * 32 + kq * 8];
        if (j + 3 < 32) stageB(j + 3);
        __builtin_amdgcn_s_setprio(1);
#pragma unroll
        for (int mi = 0; mi < 4; mi++)
#pragma unroll
            for (int ni = 0; ni < 4; ni++)
                acc[4 + mi][ni] = __builtin_amdgcn_mfma_f32_16x16x32_bf16(
                    af[mi], bfr[ni], acc[4 + mi][ni], 0, 0, 0);
        __builtin_amdgcn_s_setprio(0);
    }

    // epilogue: C/D layout col=lane&15, row=(lane>>4)*4+reg
    const int col0 = n0 + wc * 64 + fr;
    const int rbase = m0 + wr * 128 + kq * 4;
#pragma unroll
    for (int a = 0; a < 8; a++)
#pragma unroll
        for (int ni = 0; ni < 4; ni++)
#pragma unroll
            for (int r = 0; r < 4; r++)
                C[(size_t)(rbase + a * 16 + r) * 2048 + col0 + ni * 16] =
                    f2bf(acc[a][ni][r]);
}

// ---- triangular job decode for the S stage ------------------------------

__device__ __forceinline__ void tri_decode(int r2, int& mb, int& nb) {
    mb = (int)((sqrtf(8.0f * r2 + 1.0f) - 1.0f) * 0.5f);
    while ((mb + 1) * (mb + 2) / 2 <= r2) mb++;
    while (mb * (mb + 1) / 2 > r2) mb--;
    nb = r2 - mb * (mb + 1) / 2;
}

// ---- stage C: S = scale * Q K^T, lower-triangle blocks only -------------
// 544 blocks; max CU gets 3 blocks = 48 iters.

__global__ __launch_bounds__(256, 4) void gemm_s(
    const unsigned short* __restrict__ qk, unsigned short* __restrict__ S) {
    int bz = blockIdx.x / 136;
    int mb, nb;
    tri_decode(blockIdx.x - bz * 136, mb, nb);
    const unsigned short* Q = qk + (size_t)bz * 2048 * 2048;
    gemm_core(Q, 2048, Q + 1024, 2048, S + (size_t)bz * 2048 * 2048, 2048,
              true, 1024, 0.03125f, mb * BM, nb * BN);
}

// ---- stage D: softmax (causal, in place)  MERGED WITH  vt = WvT @ xb^T --
// Softmax: ONE row per wave (2048 blocks x 4 waves = 8192 rows exactly).

__global__ __launch_bounds__(256, 4) void sm_vt(
    unsigned short* __restrict__ S, const unsigned short* __restrict__ wTv,
    const unsigned short* __restrict__ xb, unsigned short* __restrict__ vt) {
    int bid = blockIdx.x;
    if (bid < 512) {  // vt: 8 m-blocks x 64 n-blocks (M=1024 WvT, N=8192 xb)
        gemm_core_db(wTv, 1024, xb, 1024, vt, 8192, true, 1024, 1.0f,
                     (bid >> 6) * BM, (bid & 63) * BN);
        return;
    }
    // softmax: one wave per row, full row in registers (32 f32/lane)
    int lane = threadIdx.x & 63;
    int row = (bid - 512) * 4 + (threadIdx.x >> 6);  // 0..8191
    int i = row & 2047;  // causal row index within batch
    unsigned short* s = S + (size_t)row * 2048;

    uint4 raw[4];
#pragma unroll
    for (int c = 0; c < 4; c++) raw[c] = ((const uint4*)s)[lane + c * 64];

    const float NEG = -1.0e30f;
    float p[32];
    float m = NEG;
#pragma unroll
    for (int c = 0; c < 4; c++) {
        const unsigned int* u = (const unsigned int*)&raw[c];
#pragma unroll
        for (int w = 0; w < 4; w++) {
            int j = c * 512 + lane * 8 + w * 2;
            float f0 = bf2f_hi(u[w] << 16);
            float f1 = bf2f_hi(u[w] & 0xffff0000u);
            f0 = (j <= i) ? f0 : NEG;
            f1 = (j + 1 <= i) ? f1 : NEG;
            p[c * 8 + w * 2] = f0;
            p[c * 8 + w * 2 + 1] = f1;
            m = fmaxf(m, fmaxf(f0, f1));
        }
    }
#pragma unroll
    for (int o = 32; o > 0; o >>= 1) m = fmaxf(m, __shfl_xor(m, o));

    float sum = 0.f;
#pragma unroll
    for (int t = 0; t < 32; t++) {
        p[t] = __expf(p[t] - m);
        sum += p[t];
    }
#pragma unroll
    for (int o = 32; o > 0; o >>= 1) sum += __shfl_xor(sum, o);
    float inv = 1.0f / sum;

#pragma unroll
    for (int c = 0; c < 4; c++) {
        uint4 out;
        unsigned int* u = (unsigned int*)&out;
#pragma unroll
        for (int w = 0; w < 4; w++) {
            unsigned int lo = f2bf(p[c * 8 + w * 2] * inv);
            unsigned int hi = f2bf(p[c * 8 + w * 2 + 1] * inv);
            u[w] = lo | (hi << 16);
        }
        ((uint4*)s)[lane + c * 64] = out;
    }
}

// ---- stage E: O = P @ V, complementary kend pairing ---------------------
// Round-robin block->CU: CU c gets blocks c and c+256; per-CU iters = 34,
// uniform.  R3 dbuf core + padded-stride layout.

__global__ __launch_bounds__(256, 4) void gemm_pv(
    const unsigned short* __restrict__ S, const unsigned short* __restrict__ vt,
    float* __restrict__ out) {
    int b = blockIdx.x;
    int j = b < 256 ? b : 767 - b;
    int mb = j >> 5;
    int rem = j & 31;
    int bz = rem >> 3, nb = rem & 7;
    int kend = (mb + 1) * 128;  // P[i][j]==0 for j>i
    gemm_core_db(S + (size_t)bz * 2048 * 2048, 2048, vt + (size_t)bz * 2048,
                 8192, out + (size_t)bz * 2048 * 1024, 1024, false, kend, 1.0f,
                 mb * BM, nb * BN);
}

// ---- launch -------------------------------------------------------------

extern "C" void kernel_launch(void* const* d_in, const int* in_sizes, int n_in,
                              void* d_out, int out_size, void* d_ws,
                              size_t ws_size, hipStream_t stream) {
    const float* x = (const float*)d_in[0];
    const float* Wq = (const float*)d_in[1];
    const float* Wk = (const float*)d_in[2];
    const float* Wv = (const float*)d_in[3];
    // causal_mask (d_in[4]) is always 1 in this problem — hardcoded causal.

    char* ws = (char*)d_ws;
    // layout (bytes):
    //   qk [8192][2048] bf16  : 0        .. 33554432   (Q cols 0..1023, K cols 1024..2047)
    //   S  [4][2048][2048]    : 33554432 .. 67108864
    //   vt [1024][8192] bf16  : 67108864 .. 83886080   (V^T, batches side-by-side cols)
    //   xb [8192][1024] bf16  : 83886080 .. 100663296
    //   wT [3][1024][1024]    : 100663296.. 106954752
    unsigned short* qk = (unsigned short*)(ws);
    unsigned short* S = (unsigned short*)(ws + 33554432);
    unsigned short* vt = (unsigned short*)(ws + 67108864);
    unsigned short* xb = (unsigned short*)(ws + 83886080);
    unsigned short* wT = (unsigned short*)(ws + 100663296);

    // A. x->bf16 (8192 blocks) + W->W^T bf16 (3072 blocks), one dispatch
    prep<<<11264, 256, 0, stream>>>(x, Wq, Wk, Wv, xb, wT);
    // B. qk = xb @ [Wq|Wk]   (M=8192, N=2048, K=1024) — 256 blocks, 1/CU
    gemm_qk8<<<dim3(8, 32), 512, 0, stream>>>(xb, wT, qk);
    // C. S = scale * Q K^T — 544 lower-triangle blocks only
    gemm_s<<<544, 256, 0, stream>>>(qk, S);
    // D. softmax (2048 light blocks) + vt GEMM (512 blocks), one dispatch
    sm_vt<<<2560, 256, 0, stream>>>(S, wT + 2 * 1024 * 1024, xb, vt);
    // E. O = P @ V — 512 blocks, complementary kend pairing
    gemm_pv<<<512, 256, 0, stream>>>(S, vt, (float*)d_out);
}